// Round 7
// baseline (45.707 us; speedup 1.0000x reference)
//
#include <hip/hip_runtime.h>

#define D_MODEL 1024
#define SEQ_L   4096
#define TC      16                 // timesteps per thread
#define CPR     (SEQ_L / TC)       // 256 threads per block (one block per d)

#define INV2PI 0.15915494309189535f

typedef float f2 __attribute__((ext_vector_type(2)));

// out[d][t]: t==0 -> h0[d]; t>=1 -> sum_m Re( (Rre+i*Rim) * (r e^{i th})^(t-1) )
//
// One block per d (params block-uniform -> scalar loads). Thread c owns
// t = 16c..16c+15 for ALL 16 modes; zero cross-lane traffic, zero LDS.
// Per mode: direct seed at q0 = 16c-1 via hw transcendentals in revolution
// domain; then ORDER-2 REAL recurrence v_q = a*v_{q-1} - b*v_{q-2}
// (a = 2 r cos th, b = r^2; roots inside unit circle -> stable).
// The 16 chains are packed as 8 float2 chains -> v_pk_{mul,fma,add}_f32:
// 24 packed insts per timestep instead of 48 scalar.
__global__ __launch_bounds__(256, 4) void pcmf_kernel(
    const float* __restrict__ r_,
    const float* __restrict__ th_,
    const float* __restrict__ Rre_,
    const float* __restrict__ Rim_,
    const float* __restrict__ h0_,
    float* __restrict__ out)
{
    const int d  = blockIdx.x;          // 0..1023, block-uniform
    const int c  = threadIdx.x;         // 0..255
    const int t0 = c * TC;
    const float q0f = (float)(t0 - 1);  // power index of first element

    f2 A[8], B[8], V1[8], V2[8];

#pragma unroll
    for (int m = 0; m < 16; ++m) {
        const int idx  = m * D_MODEL + d;    // uniform -> s_load
        const float r  = r_[idx];
        const float th = th_[idx];
        const float Re = Rre_[idx];
        const float Im = Rim_[idx];

        // W = r e^{i th} (hw trig in revolutions; th/(2pi) in [0,1))
        const float rev = th * INV2PI;
        const float sn1 = __builtin_amdgcn_sinf(rev);
        const float cs1 = __builtin_amdgcn_cosf(rev);
        const float Wx  = r * cs1;
        const float Wy  = r * sn1;

        // u = (Re + i Im) * r^q0 * e^{i q0 th}
        const float fr  = __builtin_amdgcn_fractf(q0f * rev);
        const float sn0 = __builtin_amdgcn_sinf(fr);
        const float cs0 = __builtin_amdgcn_cosf(fr);
        const float dec = __builtin_amdgcn_exp2f(q0f * __builtin_amdgcn_logf(r));
        const float x   = dec * cs0;
        const float y   = dec * sn0;
        const float v2s = fmaf(Re, x, -(Im * y));   // v_{q0} = Re(u)
        const float uys = fmaf(Re, y,   Im * x);
        const float v1s = fmaf(v2s, Wx, -(uys * Wy)); // v_{q0+1} = Re(u*W)

        const int p = m >> 1, l = m & 1;            // pack 2 modes per f2 lane
        A[p][l]  = 2.0f * Wx;                       // 2 r cos th
        B[p][l]  = r * r;                           // r^2
        V2[p][l] = v2s;
        V1[p][l] = v1s;
    }

    f2 acc[TC];
    acc[0] = V2[0]; acc[1] = V1[0];
#pragma unroll
    for (int p = 1; p < 8; ++p) {
        acc[0] += V2[p];                            // vals[0] = sum v_{q0}
        acc[1] += V1[p];                            // vals[1] = sum v_{q0+1}
    }

    // ---- 14 steps x 8 packed order-2 chains: pk_mul + pk_fma + pk_add ----
#pragma unroll
    for (int j = 2; j < TC; ++j) {
        f2 s = (f2)(0.0f);
#pragma unroll
        for (int p = 0; p < 8; ++p) {
            const f2 vn = A[p] * V1[p] - B[p] * V2[p];  // contracts to pk_fma
            s += vn;
            V2[p] = V1[p];
            V1[p] = vn;
        }
        acc[j] = s;
    }

    float vals[TC];
#pragma unroll
    for (int j = 0; j < TC; ++j) vals[j] = acc[j][0] + acc[j][1];

    if (c == 0) vals[0] = h0_[d];

    float* p = out + (size_t)d * SEQ_L + t0;
#pragma unroll
    for (int q = 0; q < TC / 4; ++q)
        *(float4*)(p + 4 * q) =
            make_float4(vals[4*q], vals[4*q+1], vals[4*q+2], vals[4*q+3]);
}

extern "C" void kernel_launch(void* const* d_in, const int* in_sizes, int n_in,
                              void* d_out, int out_size, void* d_ws, size_t ws_size,
                              hipStream_t stream) {
    // inputs: [0]=L (scalar), [1]=r, [2]=theta, [3]=R_re, [4]=R_im, [5]=h_0
    const float* r_   = (const float*)d_in[1];
    const float* th_  = (const float*)d_in[2];
    const float* Rre_ = (const float*)d_in[3];
    const float* Rim_ = (const float*)d_in[4];
    const float* h0_  = (const float*)d_in[5];
    float* out = (float*)d_out;

    pcmf_kernel<<<D_MODEL, CPR, 0, stream>>>(r_, th_, Rre_, Rim_, h0_, out);
}

// Round 9
// 16.303 us; speedup vs baseline: 2.8036x; 2.8036x over previous
//
#include <hip/hip_runtime.h>

#define D_MODEL 1024
#define SEQ_L   4096
#define TC      32                 // timesteps per thread
#define CPR     (SEQ_L / TC)       // 128 threads per block (one block per d)

#define INV2PI 0.15915494309189535f

typedef float f2 __attribute__((ext_vector_type(2)));

// out[d][t]: t==0 -> h0[d]; t>=1 -> sum_m Re( (Rre+i*Rim) * (r e^{i th})^(t-1) )
//
// One block per d (params block-uniform -> scalar loads). Thread c owns
// t = 32c..32c+31 for ALL 16 modes. Order-2 real recurrence
// v_q = a*v_{q-1} - b*v_{q-2} (a = 2 r cos th, b = r^2), seeded at q0=32c-1
// via hw transcendentals in revolution domain.
// 16 chains packed as 8 f2 chains in NAMED variables (ext_vector ARRAYS go
// to scratch -- rule #20; named vars stay in VGPRs) -> v_pk_mul/fma/add.
__global__ __launch_bounds__(128, 4) void pcmf_kernel(
    const float* __restrict__ r_,
    const float* __restrict__ th_,
    const float* __restrict__ Rre_,
    const float* __restrict__ Rim_,
    const float* __restrict__ h0_,
    float* __restrict__ out)
{
    const int d  = blockIdx.x;          // 0..1023, block-uniform
    const int c  = threadIdx.x;         // 0..127
    const int t0 = c * TC;
    const float q0f = (float)(t0 - 1);  // power index of first element

    f2 A0, A1, A2, A3, A4, A5, A6, A7;
    f2 B0, B1, B2, B3, B4, B5, B6, B7;
    f2 P0, P1, P2, P3, P4, P5, P6, P7;   // v_{q-1}
    f2 Q0, Q1, Q2, Q3, Q4, Q5, Q6, Q7;   // v_{q-2}

#define SEED(m, n, FLD) do {                                              \
        const int   idx = (m) * D_MODEL + d;   /* uniform -> s_load */    \
        const float r   = r_[idx];                                        \
        const float th  = th_[idx];                                       \
        const float Re  = Rre_[idx];                                      \
        const float Im  = Rim_[idx];                                      \
        const float rev = th * INV2PI;                                    \
        const float sn1 = __builtin_amdgcn_sinf(rev);                     \
        const float cs1 = __builtin_amdgcn_cosf(rev);                     \
        const float Wx  = r * cs1;                                        \
        const float Wy  = r * sn1;                                        \
        const float fr  = __builtin_amdgcn_fractf(q0f * rev);             \
        const float sn0 = __builtin_amdgcn_sinf(fr);                      \
        const float cs0 = __builtin_amdgcn_cosf(fr);                      \
        const float dec = __builtin_amdgcn_exp2f(q0f * __builtin_amdgcn_logf(r)); \
        const float x   = dec * cs0;                                      \
        const float y   = dec * sn0;                                      \
        const float v2s = fmaf(Re, x, -(Im * y));      /* v_{q0}   */     \
        const float uys = fmaf(Re, y,   Im * x);                          \
        const float v1s = fmaf(v2s, Wx, -(uys * Wy));  /* v_{q0+1} */     \
        A##n.FLD = 2.0f * Wx;                                             \
        B##n.FLD = r * r;                                                 \
        Q##n.FLD = v2s;                                                   \
        P##n.FLD = v1s;                                                   \
    } while (0)

    SEED( 0, 0, x); SEED( 1, 0, y);
    SEED( 2, 1, x); SEED( 3, 1, y);
    SEED( 4, 2, x); SEED( 5, 2, y);
    SEED( 6, 3, x); SEED( 7, 3, y);
    SEED( 8, 4, x); SEED( 9, 4, y);
    SEED(10, 5, x); SEED(11, 5, y);
    SEED(12, 6, x); SEED(13, 6, y);
    SEED(14, 7, x); SEED(15, 7, y);
#undef SEED

    float vals[TC];
    {
        f2 s0 = Q0 + Q1 + Q2 + Q3 + Q4 + Q5 + Q6 + Q7;   // pk_add tree
        f2 s1 = P0 + P1 + P2 + P3 + P4 + P5 + P6 + P7;
        vals[0] = s0.x + s0.y;
        vals[1] = s1.x + s1.y;
    }

    // ---- 30 steps x 8 packed order-2 chains: pk_mul + pk_fma, pk_add tree ----
#define STEP_PAIR(n, s) do {                                     \
        const f2 t  = B##n * Q##n;                               \
        const f2 vn = __builtin_elementwise_fma(A##n, P##n, -t); \
        s += vn;                                                 \
        Q##n = P##n;                                             \
        P##n = vn;                                               \
    } while (0)

#pragma unroll
    for (int j = 2; j < TC; ++j) {
        f2 sA = (f2)(0.0f), sB = (f2)(0.0f);
        STEP_PAIR(0, sA); STEP_PAIR(1, sB);
        STEP_PAIR(2, sA); STEP_PAIR(3, sB);
        STEP_PAIR(4, sA); STEP_PAIR(5, sB);
        STEP_PAIR(6, sA); STEP_PAIR(7, sB);
        const f2 s = sA + sB;
        vals[j] = s.x + s.y;
    }
#undef STEP_PAIR

    if (c == 0) vals[0] = h0_[d];

    float* p = out + (size_t)d * SEQ_L + t0;
#pragma unroll
    for (int q = 0; q < TC / 4; ++q)
        *(float4*)(p + 4 * q) =
            make_float4(vals[4*q], vals[4*q+1], vals[4*q+2], vals[4*q+3]);
}

extern "C" void kernel_launch(void* const* d_in, const int* in_sizes, int n_in,
                              void* d_out, int out_size, void* d_ws, size_t ws_size,
                              hipStream_t stream) {
    // inputs: [0]=L (scalar), [1]=r, [2]=theta, [3]=R_re, [4]=R_im, [5]=h_0
    const float* r_   = (const float*)d_in[1];
    const float* th_  = (const float*)d_in[2];
    const float* Rre_ = (const float*)d_in[3];
    const float* Rim_ = (const float*)d_in[4];
    const float* h0_  = (const float*)d_in[5];
    float* out = (float*)d_out;

    pcmf_kernel<<<D_MODEL, CPR, 0, stream>>>(r_, th_, Rre_, Rim_, h0_, out);
}

// Round 10
// 14.258 us; speedup vs baseline: 3.2057x; 1.1434x over previous
//
#include <hip/hip_runtime.h>

#define D_MODEL 1024
#define SEQ_L   4096
#define TC      32                 // timesteps per thread
#define CPR     (SEQ_L / TC)       // 128 threads per block (one block per d)

#define INV2PI 0.15915494309189535f

typedef float f2 __attribute__((ext_vector_type(2)));

// out[d][t]: t==0 -> h0[d]; t>=1 -> sum_m Re( (Rre+i*Rim) * (r e^{i th})^(t-1) )
//
// One block per d (params block-uniform -> scalar loads). Thread c owns
// t = 32c..32c+31 for ALL 16 modes. Order-2 real recurrence
// v_q = a*v_{q-1} - b*v_{q-2} (a = 2 r cos th, b = r^2), seeded at q0=32c-1
// via hw transcendentals in revolution domain. 16 chains packed as 8 f2
// chains in NAMED variables (vector arrays spill to scratch -- rule #20).
//
// R10 change: stores were the suspect (per-thread-contiguous layout scatters
// each wave store across 64 cache lines). Stage vals[] in LDS (padded rows,
// 36 floats = 144 B, 16B-aligned) and write out coalesced: per iteration the
// block stores 2 KB contiguous via float4.
__global__ __launch_bounds__(128, 4) void pcmf_kernel(
    const float* __restrict__ r_,
    const float* __restrict__ th_,
    const float* __restrict__ Rre_,
    const float* __restrict__ Rim_,
    const float* __restrict__ h0_,
    float* __restrict__ out)
{
    const int d  = blockIdx.x;          // 0..1023, block-uniform
    const int c  = threadIdx.x;         // 0..127
    const int t0 = c * TC;
    const float q0f = (float)(t0 - 1);  // power index of first element

    f2 A0, A1, A2, A3, A4, A5, A6, A7;
    f2 B0, B1, B2, B3, B4, B5, B6, B7;
    f2 P0, P1, P2, P3, P4, P5, P6, P7;   // v_{q-1}
    f2 Q0, Q1, Q2, Q3, Q4, Q5, Q6, Q7;   // v_{q-2}

#define SEED(m, n, FLD) do {                                              \
        const int   idx = (m) * D_MODEL + d;   /* uniform -> s_load */    \
        const float r   = r_[idx];                                        \
        const float th  = th_[idx];                                       \
        const float Re  = Rre_[idx];                                      \
        const float Im  = Rim_[idx];                                      \
        const float rev = th * INV2PI;                                    \
        const float sn1 = __builtin_amdgcn_sinf(rev);                     \
        const float cs1 = __builtin_amdgcn_cosf(rev);                     \
        const float Wx  = r * cs1;                                        \
        const float Wy  = r * sn1;                                        \
        const float fr  = __builtin_amdgcn_fractf(q0f * rev);             \
        const float sn0 = __builtin_amdgcn_sinf(fr);                      \
        const float cs0 = __builtin_amdgcn_cosf(fr);                      \
        const float dec = __builtin_amdgcn_exp2f(q0f * __builtin_amdgcn_logf(r)); \
        const float x   = dec * cs0;                                      \
        const float y   = dec * sn0;                                      \
        const float v2s = fmaf(Re, x, -(Im * y));      /* v_{q0}   */     \
        const float uys = fmaf(Re, y,   Im * x);                          \
        const float v1s = fmaf(v2s, Wx, -(uys * Wy));  /* v_{q0+1} */     \
        A##n.FLD = 2.0f * Wx;                                             \
        B##n.FLD = r * r;                                                 \
        Q##n.FLD = v2s;                                                   \
        P##n.FLD = v1s;                                                   \
    } while (0)

    SEED( 0, 0, x); SEED( 1, 0, y);
    SEED( 2, 1, x); SEED( 3, 1, y);
    SEED( 4, 2, x); SEED( 5, 2, y);
    SEED( 6, 3, x); SEED( 7, 3, y);
    SEED( 8, 4, x); SEED( 9, 4, y);
    SEED(10, 5, x); SEED(11, 5, y);
    SEED(12, 6, x); SEED(13, 6, y);
    SEED(14, 7, x); SEED(15, 7, y);
#undef SEED

    float vals[TC];
    {
        f2 s0 = Q0 + Q1 + Q2 + Q3 + Q4 + Q5 + Q6 + Q7;   // pk_add tree
        f2 s1 = P0 + P1 + P2 + P3 + P4 + P5 + P6 + P7;
        vals[0] = s0.x + s0.y;
        vals[1] = s1.x + s1.y;
    }

    // ---- 30 steps x 8 packed order-2 chains: pk_mul + pk_fma, pk_add tree ----
#define STEP_PAIR(n, s) do {                                     \
        const f2 t  = B##n * Q##n;                               \
        const f2 vn = __builtin_elementwise_fma(A##n, P##n, -t); \
        s += vn;                                                 \
        Q##n = P##n;                                             \
        P##n = vn;                                               \
    } while (0)

#pragma unroll
    for (int j = 2; j < TC; ++j) {
        f2 sA = (f2)(0.0f), sB = (f2)(0.0f);
        STEP_PAIR(0, sA); STEP_PAIR(1, sB);
        STEP_PAIR(2, sA); STEP_PAIR(3, sB);
        STEP_PAIR(4, sA); STEP_PAIR(5, sB);
        STEP_PAIR(6, sA); STEP_PAIR(7, sB);
        const f2 s = sA + sB;
        vals[j] = s.x + s.y;
    }
#undef STEP_PAIR

    if (c == 0) vals[0] = h0_[d];

    // ---- stage in LDS (padded 36-float rows), then coalesced stores ----
    __shared__ float lds[CPR * 36];                  // 18 KB
    float* row = &lds[c * 36];
#pragma unroll
    for (int q = 0; q < TC / 4; ++q)
        *(float4*)(row + 4 * q) =
            make_float4(vals[4*q], vals[4*q+1], vals[4*q+2], vals[4*q+3]);

    __syncthreads();

    float* outd = out + (size_t)d * SEQ_L;
#pragma unroll
    for (int j2 = 0; j2 < 8; ++j2) {
        const int tstart = c * 4 + j2 * 512;         // block writes 2KB/iter contiguous
        const int rrow   = tstart >> 5;              // source thread row
        const int qq     = (tstart & 31) >> 2;       // float4 slot in row
        const float4 v = *(const float4*)(&lds[rrow * 36 + qq * 4]);
        *(float4*)(outd + tstart) = v;
    }
}

extern "C" void kernel_launch(void* const* d_in, const int* in_sizes, int n_in,
                              void* d_out, int out_size, void* d_ws, size_t ws_size,
                              hipStream_t stream) {
    // inputs: [0]=L (scalar), [1]=r, [2]=theta, [3]=R_re, [4]=R_im, [5]=h_0
    const float* r_   = (const float*)d_in[1];
    const float* th_  = (const float*)d_in[2];
    const float* Rre_ = (const float*)d_in[3];
    const float* Rim_ = (const float*)d_in[4];
    const float* h0_  = (const float*)d_in[5];
    float* out = (float*)d_out;

    pcmf_kernel<<<D_MODEL, CPR, 0, stream>>>(r_, th_, Rre_, Rim_, h0_, out);
}